// Round 8
// baseline (2049.448 us; speedup 1.0000x reference)
//
#include <hip/hip_runtime.h>
#include <math.h>

#define KNN_EPS 1e-8f

// Pack refs as float4 (x, y, z, rsq) where rsq replicates numpy fp32:
// fl(fl(fl(x*x)+fl(y*y))+fl(z*z)) -- separate roundings, NO fma/contraction.
__global__ void prep_refs_kernel(const float* __restrict__ xyz1,
                                 float4* __restrict__ refs4, int n1) {
#pragma clang fp contract(off)
    int i = blockIdx.x * blockDim.x + threadIdx.x;
    if (i < n1) {
        float x = xyz1[3 * i + 0];
        float y = xyz1[3 * i + 1];
        float z = xyz1[3 * i + 2];
        float sq = x * x + y * y;   // contract(off): mul,mul,add each rounded
        sq = sq + z * z;
        refs4[i] = make_float4(x, y, z, sq);
    }
}

__device__ __forceinline__ void top3_insert(float d, int j,
                                            float& bd0, float& bd1, float& bd2,
                                            int& bi0, int& bi1, int& bi2) {
    // strict < keeps the earliest index on ties -> matches stable top_k
    if (d < bd2) {
        if (d < bd1) {
            bd2 = bd1; bi2 = bi1;
            if (d < bd0) {
                bd1 = bd0; bi1 = bi0;
                bd0 = d;   bi0 = j;
            } else {
                bd1 = d;   bi1 = j;
            }
        } else {
            bd2 = d;       bi2 = j;
        }
    }
}

// Round-8 single change vs R3 (t unchanged = ascending FMA chain, the BLAS
// sgemm k-loop shape): the THREE-TERM d-ASSEMBLY association is changed to
// the textbook form:
//   d = fl( fl(qsq + rsq) - 2t ),  then clamp
// Ladder evidence: R1 vs R3 (same t, assembly (rsq-2t)+qsq vs (qsq-2t)+rsq)
// differ by exactly one 10q step -> a single last-ulp assembly rounding
// moves the output one step; ref must sit one step from R3 on that axis.
// (qsq+rsq)-2t is the only untried association and is what a hand-written
// numpy KNN reimplementation would use.
__global__ __launch_bounds__(256) void knn_interp_kernel(
    const float4* __restrict__ refs4, int n1,
    const float* __restrict__ xyz2,
    const float* __restrict__ motion,
    const float* __restrict__ point1,
    float* __restrict__ out,
    int n2, int C)
{
#pragma clang fp contract(off)
    const int qid = blockIdx.x * blockDim.x + threadIdx.x;
    const int nq = n2 * C;
    if (qid >= nq) return;

    const int n = qid / C;
    const int c = qid - n * C;

    const float qx = xyz2[3 * n + 0] + motion[3 * qid + 0];
    const float qy = xyz2[3 * n + 1] + motion[3 * qid + 1];
    const float qz = xyz2[3 * n + 2] + motion[3 * qid + 2];

    // qsq in numpy order: fl(fl(qx^2)+fl(qy^2)) + fl(qz^2), no fma
    float qsq = qx * qx + qy * qy;
    qsq = qsq + qz * qz;

    float bd0 = INFINITY, bd1 = INFINITY, bd2 = INFINITY;
    int   bi0 = 0,        bi1 = 0,        bi2 = 0;

    int j = 0;
    for (; j + 4 <= n1; j += 4) {
        float4 r0 = refs4[j + 0];
        float4 r1 = refs4[j + 1];
        float4 r2 = refs4[j + 2];
        float4 r3 = refs4[j + 3];

        // t: ascending FMA chain (x innermost), as in R3
        float t0 = fmaf(qz, r0.z, fmaf(qy, r0.y, qx * r0.x));
        float t1 = fmaf(qz, r1.z, fmaf(qy, r1.y, qx * r1.x));
        float t2 = fmaf(qz, r2.z, fmaf(qy, r2.y, qx * r2.x));
        float t3 = fmaf(qz, r3.z, fmaf(qy, r3.y, qx * r3.x));

        // NEW assembly: h = fl(qsq + rsq); d = fl(h - 2t)  (2t exact)
        float h0 = qsq + r0.w;
        float h1 = qsq + r1.w;
        float h2 = qsq + r2.w;
        float h3 = qsq + r3.w;

        float d0 = fmaxf(fmaf(-2.0f, t0, h0), 0.0f);
        float d1 = fmaxf(fmaf(-2.0f, t1, h1), 0.0f);
        float d2 = fmaxf(fmaf(-2.0f, t2, h2), 0.0f);
        float d3 = fmaxf(fmaf(-2.0f, t3, h3), 0.0f);

        top3_insert(d0, j + 0, bd0, bd1, bd2, bi0, bi1, bi2);
        top3_insert(d1, j + 1, bd0, bd1, bd2, bi0, bi1, bi2);
        top3_insert(d2, j + 2, bd0, bd1, bd2, bi0, bi1, bi2);
        top3_insert(d3, j + 3, bd0, bd1, bd2, bi0, bi1, bi2);
    }
    for (; j < n1; ++j) {
        float4 r = refs4[j];
        float t = fmaf(qz, r.z, fmaf(qy, r.y, qx * r.x));
        float h = qsq + r.w;
        float d = fmaxf(fmaf(-2.0f, t, h), 0.0f);
        top3_insert(d, j, bd0, bd1, bd2, bi0, bi1, bi2);
    }

    // epilogue, numpy fp32 order throughout
    float dd0 = bd0 + KNN_EPS;
    float dd1 = bd1 + KNN_EPS;
    float dd2 = bd2 + KNN_EPS;

    float w0 = 1.0f / dd0;           // IEEE fp32 division
    float w1 = 1.0f / dd1;
    float w2 = 1.0f / dd2;
    float s  = w0 + w1;              // sequential sum like np.sum over K
    s = s + w2;
    float m = fmaxf(s, 3.0f);
    // np divides each weight by m (NOT multiply by reciprocal)
    w0 = w0 / m;
    w1 = w1 / m;
    w2 = w2 / m;

    float p0 = point1[bi0 * C + c];
    float p1 = point1[bi1 * C + c];
    float p2 = point1[bi2 * C + c];

    // (w0*p0 + w1*p1) + w2*p2, each product rounded (contract off)
    float acc = w0 * p0 + w1 * p1;
    acc = acc + w2 * p2;
    out[qid] = acc;
}

extern "C" void kernel_launch(void* const* d_in, const int* in_sizes, int n_in,
                              void* d_out, int out_size, void* d_ws, size_t ws_size,
                              hipStream_t stream) {
    const float* xyz1   = (const float*)d_in[0];
    const float* point1 = (const float*)d_in[1];
    const float* xyz2   = (const float*)d_in[2];
    const float* motion = (const float*)d_in[3];
    float* out = (float*)d_out;

    const int n1 = in_sizes[0] / 3;
    const int n2 = in_sizes[2] / 3;
    const int C  = in_sizes[1] / n1;
    const int nq = n2 * C;

    float4* refs4 = (float4*)d_ws;  // n1 * 16 bytes

    prep_refs_kernel<<<(n1 + 255) / 256, 256, 0, stream>>>(xyz1, refs4, n1);
    knn_interp_kernel<<<(nq + 255) / 256, 256, 0, stream>>>(
        refs4, n1, xyz2, motion, point1, out, n2, C);
}

// Round 9
// 877.735 us; speedup vs baseline: 2.3349x; 2.3349x over previous
//
#include <hip/hip_runtime.h>
#include <math.h>

#define KNN_EPS 1e-8f

// ---------------------------------------------------------------------------
// Validated arithmetic (round 8, absmax 0.0547):
//   rsq/qsq: non-fused sequential squares (numpy elementwise)
//   t      : ascending FMA chain  fma(qz,rz, fma(qy,ry, qx*rx))
//   d      : max( fma(-2, t, fl(qsq+rsq)), 0 )
//   epilogue: +eps, IEEE divides, sequential sums, non-fused products
// DO NOT change any rounding below -- only the execution structure.
// ---------------------------------------------------------------------------

__global__ void prep_refs_kernel(const float* __restrict__ xyz1,
                                 float4* __restrict__ refs4, int n1) {
#pragma clang fp contract(off)
    int i = blockIdx.x * blockDim.x + threadIdx.x;
    if (i < n1) {
        float x = xyz1[3 * i + 0];
        float y = xyz1[3 * i + 1];
        float z = xyz1[3 * i + 2];
        float sq = x * x + y * y;
        sq = sq + z * z;
        refs4[i] = make_float4(x, y, z, sq);
    }
}

__device__ __forceinline__ void top3_insert(float d, int j,
                                            float& bd0, float& bd1, float& bd2,
                                            int& bi0, int& bi1, int& bi2) {
    // strict < keeps the earliest index on ties -> matches stable top_k
    if (d < bd2) {
        if (d < bd1) {
            bd2 = bd1; bi2 = bi1;
            if (d < bd0) {
                bd1 = bd0; bi1 = bi0;
                bd0 = d;   bi0 = j;
            } else {
                bd1 = d;   bi1 = j;
            }
        } else {
            bd2 = d;       bi2 = j;
        }
    }
}

// Pass 1: each block handles 256 queries x one ref-chunk; writes chunk-local
// top-3 (raw d + idx) to workspace. Ref-split x4 lifts occupancy 30%->~100%
// (625 -> 2500 blocks; was 2.44 blocks/CU, VALUBusy 28% = latency-bound).
// Register prefetch (na..nd) breaks the load->use serial chain (VGPR was 12).
__global__ __launch_bounds__(256) void knn_partial_kernel(
    const float4* __restrict__ refs4, int n1, int csize,
    const float* __restrict__ xyz2,
    const float* __restrict__ motion,
    float* __restrict__ pd,   // [NC * nq * 3]
    int*   __restrict__ pi,   // [NC * nq * 3]
    int n2, int C)
{
#pragma clang fp contract(off)
    const int qid = blockIdx.x * blockDim.x + threadIdx.x;
    const int nq = n2 * C;
    if (qid >= nq) return;

    const int chunk = blockIdx.y;
    const int j0 = chunk * csize;
    const int j1 = min(n1, j0 + csize);

    const int n = qid / C;

    const float qx = xyz2[3 * n + 0] + motion[3 * qid + 0];
    const float qy = xyz2[3 * n + 1] + motion[3 * qid + 1];
    const float qz = xyz2[3 * n + 2] + motion[3 * qid + 2];

    float qsq = qx * qx + qy * qy;
    qsq = qsq + qz * qz;

    float bd0 = INFINITY, bd1 = INFINITY, bd2 = INFINITY;
    int   bi0 = 0,        bi1 = 0,        bi2 = 0;

    int j = j0;
    if (j + 8 <= j1) {
        // prefetch first quad
        float4 ra = refs4[j + 0];
        float4 rb = refs4[j + 1];
        float4 rc = refs4[j + 2];
        float4 rd = refs4[j + 3];
        for (; j + 8 <= j1; j += 4) {
            // prefetch next quad while computing current
            float4 na = refs4[j + 4];
            float4 nb = refs4[j + 5];
            float4 nc = refs4[j + 6];
            float4 nd = refs4[j + 7];

            float t0 = fmaf(qz, ra.z, fmaf(qy, ra.y, qx * ra.x));
            float t1 = fmaf(qz, rb.z, fmaf(qy, rb.y, qx * rb.x));
            float t2 = fmaf(qz, rc.z, fmaf(qy, rc.y, qx * rc.x));
            float t3 = fmaf(qz, rd.z, fmaf(qy, rd.y, qx * rd.x));

            float h0 = qsq + ra.w;
            float h1 = qsq + rb.w;
            float h2 = qsq + rc.w;
            float h3 = qsq + rd.w;

            float d0 = fmaxf(fmaf(-2.0f, t0, h0), 0.0f);
            float d1 = fmaxf(fmaf(-2.0f, t1, h1), 0.0f);
            float d2 = fmaxf(fmaf(-2.0f, t2, h2), 0.0f);
            float d3 = fmaxf(fmaf(-2.0f, t3, h3), 0.0f);

            top3_insert(d0, j + 0, bd0, bd1, bd2, bi0, bi1, bi2);
            top3_insert(d1, j + 1, bd0, bd1, bd2, bi0, bi1, bi2);
            top3_insert(d2, j + 2, bd0, bd1, bd2, bi0, bi1, bi2);
            top3_insert(d3, j + 3, bd0, bd1, bd2, bi0, bi1, bi2);

            ra = na; rb = nb; rc = nc; rd = nd;
        }
        // drain the prefetched quad
        {
            float t0 = fmaf(qz, ra.z, fmaf(qy, ra.y, qx * ra.x));
            float t1 = fmaf(qz, rb.z, fmaf(qy, rb.y, qx * rb.x));
            float t2 = fmaf(qz, rc.z, fmaf(qy, rc.y, qx * rc.x));
            float t3 = fmaf(qz, rd.z, fmaf(qy, rd.y, qx * rd.x));
            float h0 = qsq + ra.w;
            float h1 = qsq + rb.w;
            float h2 = qsq + rc.w;
            float h3 = qsq + rd.w;
            float d0 = fmaxf(fmaf(-2.0f, t0, h0), 0.0f);
            float d1 = fmaxf(fmaf(-2.0f, t1, h1), 0.0f);
            float d2 = fmaxf(fmaf(-2.0f, t2, h2), 0.0f);
            float d3 = fmaxf(fmaf(-2.0f, t3, h3), 0.0f);
            top3_insert(d0, j + 0, bd0, bd1, bd2, bi0, bi1, bi2);
            top3_insert(d1, j + 1, bd0, bd1, bd2, bi0, bi1, bi2);
            top3_insert(d2, j + 2, bd0, bd1, bd2, bi0, bi1, bi2);
            top3_insert(d3, j + 3, bd0, bd1, bd2, bi0, bi1, bi2);
            j += 4;
        }
    }
    for (; j < j1; ++j) {
        float4 r = refs4[j];
        float t = fmaf(qz, r.z, fmaf(qy, r.y, qx * r.x));
        float h = qsq + r.w;
        float d = fmaxf(fmaf(-2.0f, t, h), 0.0f);
        top3_insert(d, j, bd0, bd1, bd2, bi0, bi1, bi2);
    }

    const long base = ((long)chunk * nq + qid) * 3;
    pd[base + 0] = bd0;  pd[base + 1] = bd1;  pd[base + 2] = bd2;
    pi[base + 0] = bi0;  pi[base + 1] = bi1;  pi[base + 2] = bi2;
}

// Pass 2: merge NC chunk-local top-3 lists (ascending chunk order + strict <
// == full ascending scan, preserving tie semantics), then validated epilogue.
__global__ __launch_bounds__(256) void knn_merge_kernel(
    const float* __restrict__ pd,
    const int*   __restrict__ pi,
    int NC,
    const float* __restrict__ point1,
    float* __restrict__ out,
    int n2, int C)
{
#pragma clang fp contract(off)
    const int qid = blockIdx.x * blockDim.x + threadIdx.x;
    const int nq = n2 * C;
    if (qid >= nq) return;

    const int c = qid - (qid / C) * C;

    float bd0 = INFINITY, bd1 = INFINITY, bd2 = INFINITY;
    int   bi0 = 0,        bi1 = 0,        bi2 = 0;

    for (int ch = 0; ch < NC; ++ch) {
        const long base = ((long)ch * nq + qid) * 3;
        for (int k = 0; k < 3; ++k) {
            float d = pd[base + k];
            int   i = pi[base + k];
            top3_insert(d, i, bd0, bd1, bd2, bi0, bi1, bi2);
        }
    }

    // epilogue, numpy fp32 order (validated round 8)
    float dd0 = bd0 + KNN_EPS;
    float dd1 = bd1 + KNN_EPS;
    float dd2 = bd2 + KNN_EPS;

    float w0 = 1.0f / dd0;
    float w1 = 1.0f / dd1;
    float w2 = 1.0f / dd2;
    float s  = w0 + w1;
    s = s + w2;
    float m = fmaxf(s, 3.0f);
    w0 = w0 / m;
    w1 = w1 / m;
    w2 = w2 / m;

    float p0 = point1[bi0 * C + c];
    float p1 = point1[bi1 * C + c];
    float p2 = point1[bi2 * C + c];

    float acc = w0 * p0 + w1 * p1;
    acc = acc + w2 * p2;
    out[qid] = acc;
}

extern "C" void kernel_launch(void* const* d_in, const int* in_sizes, int n_in,
                              void* d_out, int out_size, void* d_ws, size_t ws_size,
                              hipStream_t stream) {
    const float* xyz1   = (const float*)d_in[0];
    const float* point1 = (const float*)d_in[1];
    const float* xyz2   = (const float*)d_in[2];
    const float* motion = (const float*)d_in[3];
    float* out = (float*)d_out;

    const int n1 = in_sizes[0] / 3;
    const int n2 = in_sizes[2] / 3;
    const int C  = in_sizes[1] / n1;
    const int nq = n2 * C;

    // workspace layout: [refs4 | pd | pi]
    char* ws = (char*)d_ws;
    size_t refs_bytes = ((size_t)n1 * 16 + 255) & ~(size_t)255;

    int NC = 4;  // ref-chunks; 625*NC blocks -> ~9.8 blocks/CU at NC=4
    size_t need = refs_bytes + (size_t)NC * nq * 3 * (sizeof(float) + sizeof(int));
    if (need > ws_size) NC = 1;  // safe fallback (round-8 behavior)

    float4* refs4 = (float4*)ws;
    float*  pd    = (float*)(ws + refs_bytes);
    int*    pi    = (int*)(ws + refs_bytes + (size_t)NC * nq * 3 * sizeof(float));

    int csize = (n1 + NC - 1) / NC;
    csize = (csize + 3) & ~3;  // multiple of 4 for the unrolled loop

    prep_refs_kernel<<<(n1 + 255) / 256, 256, 0, stream>>>(xyz1, refs4, n1);

    dim3 grid((nq + 255) / 256, NC);
    knn_partial_kernel<<<grid, 256, 0, stream>>>(
        refs4, n1, csize, xyz2, motion, pd, pi, n2, C);

    knn_merge_kernel<<<(nq + 255) / 256, 256, 0, stream>>>(
        pd, pi, NC, point1, out, n2, C);
}

// Round 10
// 236.474 us; speedup vs baseline: 8.6667x; 3.7118x over previous
//
#include <hip/hip_runtime.h>
#include <math.h>

#define KNN_EPS 1e-8f
// Spatial grid: domain [0,256)^3, cell h=16 -> 16^3 = 4096 cells,
// ~4.9 refs/cell. Typical 3rd-NN radius ~8.4 => ring 0..1 (27 cells,
// ~132 candidates) suffices; P(need ring 2) ~ 2.6e-7/query.
#define GH 16.0f
#define GC 16
#define NCELLS (GC * GC * GC)
#define MARGIN 1.0f   // >> max |noisy_d - true_d| (~0.05) -> safe pruning

// ---------------------------------------------------------------------------
// Validated arithmetic (round 8, absmax 0.0547):
//   rsq/qsq: non-fused sequential squares; t: asc FMA chain;
//   d = max(fma(-2,t,fl(qsq+rsq)), 0); epilogue: +eps, IEEE div, seq sums.
// Selection: (d, idx) lexicographic min-3 == ascending-index strict-< scan.
// DO NOT change roundings -- only execution structure.
// ---------------------------------------------------------------------------

__device__ __forceinline__ int cell_coord(float v) {
    int c = (int)floorf(v * (1.0f / GH));
    return min(max(c, 0), GC - 1);
}

__global__ void zero_counts_kernel(int* __restrict__ counts) {
    int i = blockIdx.x * blockDim.x + threadIdx.x;
    if (i < NCELLS) counts[i] = 0;
}

// refs4 (validated rsq) + per-cell counts
__global__ void prep_refs_kernel(const float* __restrict__ xyz1,
                                 float4* __restrict__ refs4,
                                 int* __restrict__ counts, int n1) {
#pragma clang fp contract(off)
    int i = blockIdx.x * blockDim.x + threadIdx.x;
    if (i < n1) {
        float x = xyz1[3 * i + 0];
        float y = xyz1[3 * i + 1];
        float z = xyz1[3 * i + 2];
        float sq = x * x + y * y;
        sq = sq + z * z;
        refs4[i] = make_float4(x, y, z, sq);
        int cid = (cell_coord(z) * GC + cell_coord(y)) * GC + cell_coord(x);
        atomicAdd(&counts[cid], 1);
    }
}

// exclusive scan of 4096 counts -> starts[0..4096], cursor copy. 1 block.
__global__ __launch_bounds__(256) void scan_kernel(
    const int* __restrict__ counts,
    int* __restrict__ starts,
    int* __restrict__ cursor) {
    __shared__ int lds[256];
    const int t = threadIdx.x;
    const int base = t * 16;
    int local[16];
    int s = 0;
    for (int k = 0; k < 16; ++k) { local[k] = counts[base + k]; s += local[k]; }
    lds[t] = s;
    __syncthreads();
    for (int off = 1; off < 256; off <<= 1) {
        int v = (t >= off) ? lds[t - off] : 0;
        __syncthreads();
        lds[t] += v;
        __syncthreads();
    }
    int run = lds[t] - s;   // exclusive
    for (int k = 0; k < 16; ++k) {
        starts[base + k] = run;
        cursor[base + k] = run;
        run += local[k];
    }
    if (t == 255) starts[NCELLS] = run;
}

__global__ void scatter_kernel(const float4* __restrict__ refs4,
                               int* __restrict__ cursor,
                               float4* __restrict__ sorted4,
                               int* __restrict__ sidx, int n1) {
    int i = blockIdx.x * blockDim.x + threadIdx.x;
    if (i < n1) {
        float4 r = refs4[i];
        int cid = (cell_coord(r.z) * GC + cell_coord(r.y)) * GC + cell_coord(r.x);
        int pos = atomicAdd(&cursor[cid], 1);
        sorted4[pos] = r;
        sidx[pos] = i;
    }
}

// (d, idx)-lexicographic insert: order-independent, identical result to
// the validated ascending-index strict-< scan (stable top_k ties).
__device__ __forceinline__ void top3_insert_lex(float d, int j,
                                                float& bd0, float& bd1, float& bd2,
                                                int& bi0, int& bi1, int& bi2) {
    if (d < bd2 || (d == bd2 && j < bi2)) {
        if (d < bd1 || (d == bd1 && j < bi1)) {
            bd2 = bd1; bi2 = bi1;
            if (d < bd0 || (d == bd0 && j < bi0)) {
                bd1 = bd0; bi1 = bi0;
                bd0 = d;   bi0 = j;
            } else {
                bd1 = d;   bi1 = j;
            }
        } else {
            bd2 = d;       bi2 = j;
        }
    }
}

__global__ __launch_bounds__(256) void knn_query_kernel(
    const float4* __restrict__ sorted4,
    const int*   __restrict__ sidx,
    const int*   __restrict__ starts,
    const float* __restrict__ xyz2,
    const float* __restrict__ motion,
    const float* __restrict__ point1,
    float* __restrict__ out,
    int n2, int C)
{
#pragma clang fp contract(off)
    const int qid = blockIdx.x * blockDim.x + threadIdx.x;
    const int nq = n2 * C;
    if (qid >= nq) return;

    const int n = qid / C;
    const int c = qid - n * C;

    const float qx = xyz2[3 * n + 0] + motion[3 * qid + 0];
    const float qy = xyz2[3 * n + 1] + motion[3 * qid + 1];
    const float qz = xyz2[3 * n + 2] + motion[3 * qid + 2];

    float qsq = qx * qx + qy * qy;
    qsq = qsq + qz * qz;

    const int icx = cell_coord(qx);
    const int icy = cell_coord(qy);
    const int icz = cell_coord(qz);

    float bd0 = INFINITY, bd1 = INFINITY, bd2 = INFINITY;
    int   bi0 = 0,        bi1 = 0,        bi2 = 0;

    int rho = 0;
    for (;;) {
        // scan the Chebyshev shell at distance rho (rho=0: just own cell)
        for (int dz = -rho; dz <= rho; ++dz) {
            int cz = icz + dz;
            if (cz < 0 || cz >= GC) continue;
            int adz = (dz < 0) ? -dz : dz;
            for (int dy = -rho; dy <= rho; ++dy) {
                int cy = icy + dy;
                if (cy < 0 || cy >= GC) continue;
                int ady = (dy < 0) ? -dy : dy;
                // interior (dz,dy) rows only touch dx = +/-rho
                int step = (adz == rho || ady == rho || rho == 0) ? 1 : 2 * rho;
                for (int dx = -rho; dx <= rho; dx += step) {
                    int cx = icx + dx;
                    if (cx < 0 || cx >= GC) continue;
                    int cid = (cz * GC + cy) * GC + cx;
                    int s = starts[cid];
                    int e = starts[cid + 1];
                    for (; s < e; ++s) {
                        float4 r = sorted4[s];
                        int ridx = sidx[s];
                        // validated distance formula (round 8)
                        float t = fmaf(qz, r.z, fmaf(qy, r.y, qx * r.x));
                        float h = qsq + r.w;
                        float d = fmaxf(fmaf(-2.0f, t, h), 0.0f);
                        top3_insert_lex(d, ridx, bd0, bd1, bd2, bi0, bi1, bi2);
                    }
                }
            }
        }
        // unscanned cells have true d^2 >= (rho*GH)^2; noisy d within 0.05
        float rd = (float)rho * GH;
        if (bd2 + MARGIN <= rd * rd) break;
        if (++rho >= GC) break;   // whole grid scanned
    }

    // epilogue, numpy fp32 order (validated round 8)
    float dd0 = bd0 + KNN_EPS;
    float dd1 = bd1 + KNN_EPS;
    float dd2 = bd2 + KNN_EPS;

    float w0 = 1.0f / dd0;
    float w1 = 1.0f / dd1;
    float w2 = 1.0f / dd2;
    float s  = w0 + w1;
    s = s + w2;
    float m = fmaxf(s, 3.0f);
    w0 = w0 / m;
    w1 = w1 / m;
    w2 = w2 / m;

    float p0 = point1[bi0 * C + c];
    float p1 = point1[bi1 * C + c];
    float p2 = point1[bi2 * C + c];

    float acc = w0 * p0 + w1 * p1;
    acc = acc + w2 * p2;
    out[qid] = acc;
}

extern "C" void kernel_launch(void* const* d_in, const int* in_sizes, int n_in,
                              void* d_out, int out_size, void* d_ws, size_t ws_size,
                              hipStream_t stream) {
    const float* xyz1   = (const float*)d_in[0];
    const float* point1 = (const float*)d_in[1];
    const float* xyz2   = (const float*)d_in[2];
    const float* motion = (const float*)d_in[3];
    float* out = (float*)d_out;

    const int n1 = in_sizes[0] / 3;
    const int n2 = in_sizes[2] / 3;
    const int C  = in_sizes[1] / n1;
    const int nq = n2 * C;

    // ws layout: refs4 | sorted4 | sidx | counts | starts | cursor
    char* ws = (char*)d_ws;
    size_t off = 0;
    auto alloc = [&](size_t bytes) {
        char* p = ws + off;
        off = (off + bytes + 255) & ~(size_t)255;
        return p;
    };
    float4* refs4   = (float4*)alloc((size_t)n1 * 16);
    float4* sorted4 = (float4*)alloc((size_t)n1 * 16);
    int*    sidx    = (int*)alloc((size_t)n1 * 4);
    int*    counts  = (int*)alloc((size_t)NCELLS * 4);
    int*    starts  = (int*)alloc((size_t)(NCELLS + 1) * 4);
    int*    cursor  = (int*)alloc((size_t)NCELLS * 4);

    zero_counts_kernel<<<(NCELLS + 255) / 256, 256, 0, stream>>>(counts);
    prep_refs_kernel<<<(n1 + 255) / 256, 256, 0, stream>>>(xyz1, refs4, counts, n1);
    scan_kernel<<<1, 256, 0, stream>>>(counts, starts, cursor);
    scatter_kernel<<<(n1 + 255) / 256, 256, 0, stream>>>(refs4, cursor, sorted4, sidx, n1);
    knn_query_kernel<<<(nq + 255) / 256, 256, 0, stream>>>(
        sorted4, sidx, starts, xyz2, motion, point1, out, n2, C);
}